// Round 10
// baseline (28.923 us; speedup 1.0000x reference)
//
#include <hip/hip_runtime.h>

#define IMG_W 512
#define IMG_H 512
#define OUT_W 510
#define OUT_H 510
#define NPLANE 48                          // 16 batches * 3 channels
#define BANDR 8                            // output rows per block
#define INR (BANDR + 2)                    // 10 staged input rows
#define SPP ((OUT_H + BANDR - 1) / BANDR)  // 64 bands per plane (512 rows, tail masked)
#define NB (NPLANE * SPP)                  // 3072 blocks
#define EPS 1e-6f

// Block-band LDS staging: each 256-thread block stages 10 input rows x 512
// cols of BOTH images into 40KB LDS (exactly 4 blocks/CU) with
// global_load_lds (no VGPR round-trip), then 4 waves each compute 2 output
// rows reading 10-wide windows from LDS. Inter-wave duplicate loads are gone:
// global traffic = 1.25x unique (vs 2x in R9's per-wave register windows).
template <bool ATOMIC>
__global__ __launch_bounds__(256) void sobel_partial_kernel(
    const float* __restrict__ src, const float* __restrict__ tgt,
    float* __restrict__ partial)
{
    __shared__ float lds[2 * INR * IMG_W];   // [img][row][col], 40960 B

    const int tid  = threadIdx.x;
    const int lane = tid & 63;
    const int wv   = tid >> 6;               // wave 0..3

    const int s  = blockIdx.x;
    const int p  = s / SPP;
    const int y0 = (s - p * SPP) * BANDR;    // band's first output row
    const size_t pbase = (size_t)p * IMG_W * IMG_H;

    // ---- stage: 2 img x 10 rows x 512 floats ----
    // thread t covers float4 column c4 = t&127 of rows with parity t>>7;
    // per wave the LDS dest is uniform-base + lane*16 (required layout).
    const int c4    = tid & 127;             // float4 column 0..127
    const int rp    = tid >> 7;              // row parity 0/1
    const int halfF = (wv & 1) << 8;         // wave-uniform float offset (0|256)

    #pragma unroll
    for (int k = 0; k < 5; ++k) {
        const int row = 2 * k + rp;          // 0..9
        int gr = y0 + row;                   // clamp: tail rows feed masked outputs
        if (gr > IMG_H - 1) gr = IMG_H - 1;
        const float* gs = src + pbase + ((size_t)gr << 9) + (c4 << 2);
        const float* gt = tgt + pbase + ((size_t)gr << 9) + (c4 << 2);
#if __has_builtin(__builtin_amdgcn_global_load_lds)
        float* lsS = &lds[(row << 9) + halfF];
        float* lsT = &lds[((INR + row) << 9) + halfF];
        __builtin_amdgcn_global_load_lds(
            (const __attribute__((address_space(1))) void*)gs,
            (__attribute__((address_space(3))) void*)lsS, 16, 0, 0);
        __builtin_amdgcn_global_load_lds(
            (const __attribute__((address_space(1))) void*)gt,
            (__attribute__((address_space(3))) void*)lsT, 16, 0, 0);
#else
        float4 vs = *reinterpret_cast<const float4*>(gs);
        float4 vt = *reinterpret_cast<const float4*>(gt);
        *reinterpret_cast<float4*>(&lds[(row << 9) + (c4 << 2)]) = vs;
        *reinterpret_cast<float4*>(&lds[((INR + row) << 9) + (c4 << 2)]) = vt;
#endif
    }

    __syncthreads();   // drains vmcnt (global_load_lds) + lgkmcnt

    // ---- compute: wave wv -> output rows y0+2wv, y0+2wv+1 ----
    const int xb = lane << 3;                            // first col of lane
    const int hx = (xb + 8 < IMG_W) ? xb + 8 : 502;      // lane63 halo clamp (masked)

    float cm[8];
    #pragma unroll
    for (int j = 0; j < 8; ++j) cm[j] = (xb + j < OUT_W) ? 1.0f : 0.0f;

    float acc = 0.0f;

    #pragma unroll
    for (int i = 0; i < 2; ++i) {
        const int lr = (wv << 1) + i;        // local top input row (0..7)

        float ms[8];
        {   // source magnitude
            float v0[10], v1[10], v2[10];
            #pragma unroll
            for (int r = 0; r < 3; ++r) {
                const float* q = &lds[(lr + r) << 9];
                float4 A = *reinterpret_cast<const float4*>(q + xb);
                float4 B = *reinterpret_cast<const float4*>(q + xb + 4);
                float2 C = *reinterpret_cast<const float2*>(q + hx);
                float* v = (r == 0) ? v0 : (r == 1) ? v1 : v2;
                v[0]=A.x; v[1]=A.y; v[2]=A.z; v[3]=A.w;
                v[4]=B.x; v[5]=B.y; v[6]=B.z; v[7]=B.w;
                v[8]=C.x; v[9]=C.y;
            }
            #pragma unroll
            for (int j = 0; j < 8; ++j) {
                float gx = fmaf(2.0f, v1[j] - v1[j + 2],
                                (v0[j] - v0[j + 2]) + (v2[j] - v2[j + 2]));
                float gy = fmaf(2.0f, v0[j + 1], v0[j] + v0[j + 2])
                         - fmaf(2.0f, v2[j + 1], v2[j] + v2[j + 2]);
                ms[j] = __builtin_amdgcn_sqrtf(fmaf(gx, gx, gy * gy));
            }
        }

        float rowsum = 0.0f;
        {   // target magnitude + |diff|
            float v0[10], v1[10], v2[10];
            #pragma unroll
            for (int r = 0; r < 3; ++r) {
                const float* q = &lds[(INR + lr + r) << 9];
                float4 A = *reinterpret_cast<const float4*>(q + xb);
                float4 B = *reinterpret_cast<const float4*>(q + xb + 4);
                float2 C = *reinterpret_cast<const float2*>(q + hx);
                float* v = (r == 0) ? v0 : (r == 1) ? v1 : v2;
                v[0]=A.x; v[1]=A.y; v[2]=A.z; v[3]=A.w;
                v[4]=B.x; v[5]=B.y; v[6]=B.z; v[7]=B.w;
                v[8]=C.x; v[9]=C.y;
            }
            #pragma unroll
            for (int j = 0; j < 8; ++j) {
                float gx = fmaf(2.0f, v1[j] - v1[j + 2],
                                (v0[j] - v0[j + 2]) + (v2[j] - v2[j + 2]));
                float gy = fmaf(2.0f, v0[j + 1], v0[j] + v0[j + 2])
                         - fmaf(2.0f, v2[j + 1], v2[j] + v2[j + 2]);
                float mt = __builtin_amdgcn_sqrtf(fmaf(gx, gx, gy * gy));
                // |ms-mt| vs sqrt((ms-mt)^2+1e-6): drift << bf16-granular threshold
                float e  = fabsf(ms[j] - mt);
                rowsum = fmaf(e, cm[j], rowsum);
            }
        }

        const float rm = (y0 + (wv << 1) + i < OUT_H) ? 1.0f : 0.0f;
        acc = fmaf(rowsum, rm, acc);
    }

    // ---- block reduction: 4 waves ----
    #pragma unroll
    for (int off = 32; off > 0; off >>= 1)
        acc += __shfl_down(acc, off, 64);

    __shared__ float wsum[4];
    if (lane == 0) wsum[wv] = acc;
    __syncthreads();
    if (tid == 0) {
        float tot = wsum[0] + wsum[1] + wsum[2] + wsum[3];
        if (ATOMIC) atomicAdd(partial, tot * (1.0f / 16.0f));
        else        partial[blockIdx.x] = tot;
    }
}

__global__ __launch_bounds__(256) void reduce_kernel(
    const float* __restrict__ partial, float* __restrict__ out)
{
    float acc = 0.0f;
    #pragma unroll
    for (int i = threadIdx.x; i < NB; i += 256) acc += partial[i];

    #pragma unroll
    for (int off = 32; off > 0; off >>= 1)
        acc += __shfl_down(acc, off, 64);

    __shared__ float wsum[4];
    const int lane = threadIdx.x & 63;
    const int wid  = threadIdx.x >> 6;
    if (lane == 0) wsum[wid] = acc;
    __syncthreads();
    if (threadIdx.x == 0)
        out[0] = (wsum[0] + wsum[1] + wsum[2] + wsum[3]) * (1.0f / 16.0f);
}

extern "C" void kernel_launch(void* const* d_in, const int* in_sizes, int n_in,
                              void* d_out, int out_size, void* d_ws, size_t ws_size,
                              hipStream_t stream) {
    const float* src = (const float*)d_in[0];
    const float* tgt = (const float*)d_in[1];
    float* out = (float*)d_out;

    if (ws_size >= (size_t)NB * sizeof(float)) {
        float* partial = (float*)d_ws;
        sobel_partial_kernel<false><<<dim3(NB), dim3(256), 0, stream>>>(src, tgt, partial);
        reduce_kernel<<<dim3(1), dim3(256), 0, stream>>>(partial, out);
    } else {
        hipMemsetAsync(out, 0, (size_t)out_size * sizeof(float), stream);
        sobel_partial_kernel<true><<<dim3(NB), dim3(256), 0, stream>>>(src, tgt, out);
    }
}